// Round 4
// baseline (862.921 us; speedup 1.0000x reference)
//
#include <hip/hip_runtime.h>
#include <hip/hip_bf16.h>
#include <math.h>

#define N_TOK 8192
#define DIM   1024
#define HID   2048
#define NE    8

typedef __attribute__((ext_vector_type(8))) short short8;
typedef __attribute__((ext_vector_type(4))) float f32x4;

__device__ __forceinline__ unsigned short f2bf(float f) {
    unsigned int u = __builtin_bit_cast(unsigned int, f);
    unsigned int r = (u + 0x7fffu + ((u >> 16) & 1u)) >> 16;   // RNE
    return (unsigned short)r;
}

__device__ __forceinline__ short8 pack8(float4 a, float4 b) {
    short8 v;
    v[0] = (short)f2bf(a.x); v[1] = (short)f2bf(a.y);
    v[2] = (short)f2bf(a.z); v[3] = (short)f2bf(a.w);
    v[4] = (short)f2bf(b.x); v[5] = (short)f2bf(b.y);
    v[6] = (short)f2bf(b.z); v[7] = (short)f2bf(b.w);
    return v;
}

// async global -> LDS, 16 bytes per lane; lds dest must be wave-uniform base (+ lane*16 by HW)
__device__ __forceinline__ void gl_lds16(const unsigned short* g, unsigned short* l) {
    __builtin_amdgcn_global_load_lds(
        (const __attribute__((address_space(1))) void*)g,
        (__attribute__((address_space(3))) void*)l, 16, 0, 0);
}

// ---------------- gating: logits -> softmax -> top2 -> routing lists ----------------
__global__ __launch_bounds__(256) void gate_kernel(
    const float* __restrict__ x, const float* __restrict__ gw, const float* __restrict__ gb,
    float* __restrict__ usage, int* __restrict__ counts,
    int* __restrict__ lists, float* __restrict__ wts)
{
    const int wave_in_block = threadIdx.x >> 6;
    const int lane = threadIdx.x & 63;
    const int tok = blockIdx.x * 4 + wave_in_block;

    __shared__ float su[NE];
    if (threadIdx.x < NE) su[threadIdx.x] = 0.f;
    __syncthreads();

    float acc[NE];
#pragma unroll
    for (int e = 0; e < NE; e++) acc[e] = 0.f;

    const float* xr = x + (size_t)tok * DIM;
    for (int d = lane; d < DIM; d += 64) {
        float xv = xr[d];
        const float4* g4 = (const float4*)(gw + (size_t)d * NE);
        float4 ga = g4[0], gc = g4[1];
        acc[0] = fmaf(xv, ga.x, acc[0]);
        acc[1] = fmaf(xv, ga.y, acc[1]);
        acc[2] = fmaf(xv, ga.z, acc[2]);
        acc[3] = fmaf(xv, ga.w, acc[3]);
        acc[4] = fmaf(xv, gc.x, acc[4]);
        acc[5] = fmaf(xv, gc.y, acc[5]);
        acc[6] = fmaf(xv, gc.z, acc[6]);
        acc[7] = fmaf(xv, gc.w, acc[7]);
    }
#pragma unroll
    for (int e = 0; e < NE; e++) {
#pragma unroll
        for (int off = 32; off > 0; off >>= 1)
            acc[e] += __shfl_xor(acc[e], off);
    }

    if (lane == 0) {
        float lg[NE], p[NE];
        float mx = -1e30f;
#pragma unroll
        for (int e = 0; e < NE; e++) { lg[e] = acc[e] + gb[e]; mx = fmaxf(mx, lg[e]); }
        float s = 0.f;
#pragma unroll
        for (int e = 0; e < NE; e++) { p[e] = __expf(lg[e] - mx); s += p[e]; }
        float inv = 1.f / s;
#pragma unroll
        for (int e = 0; e < NE; e++) p[e] *= inv;

#pragma unroll
        for (int e = 0; e < NE; e++) atomicAdd(&su[e], p[e]);

        int e1 = 0; float v1 = p[0];
#pragma unroll
        for (int e = 1; e < NE; e++) if (p[e] > v1) { v1 = p[e]; e1 = e; }
        int e2 = -1; float v2 = -1e30f;
#pragma unroll
        for (int e = 0; e < NE; e++) if (e != e1 && p[e] > v2) { v2 = p[e]; e2 = e; }

        int pos1 = atomicAdd(&counts[e1], 1);
        lists[e1 * N_TOK + pos1] = tok * 2 + 0;
        wts[e1 * N_TOK + pos1] = v1;
        int pos2 = atomicAdd(&counts[e2], 1);
        lists[e2 * N_TOK + pos2] = tok * 2 + 1;
        wts[e2 * N_TOK + pos2] = v2;
    }
    __syncthreads();
    if (threadIdx.x < NE) atomicAdd(&usage[threadIdx.x], su[threadIdx.x]);
}

__global__ void loss_kernel(const float* __restrict__ usage, float* __restrict__ out_loss)
{
    if (threadIdx.x == 0) {
        float l = 0.f;
        for (int e = 0; e < NE; e++) {
            float u = usage[e] / (float)N_TOK;
            l += u * logf(u + 1e-9f);
        }
        *out_loss = l;
    }
}

// ---------------- x (f32) -> bf16, token-major ----------------
__global__ __launch_bounds__(256) void xconv_kernel(
    const float* __restrict__ x, unsigned short* __restrict__ xb)
{
    size_t i = ((size_t)blockIdx.x * 256 + threadIdx.x) * 8;
    float4 a = *(const float4*)(x + i);
    float4 b = *(const float4*)(x + i + 4);
    *(short8*)(xb + i) = pack8(a, b);
}

// ---------------- W (f32 [R][C]) -> WT (bf16 [C][R]) per expert ----------------
__global__ __launch_bounds__(256) void transpose_bf16_kernel(
    const float* __restrict__ in, unsigned short* __restrict__ out, int R, int C)
{
    __shared__ float Ls[64][65];
    const int e = blockIdx.z;
    const float* in_e = in + (size_t)e * R * C;
    unsigned short* out_e = out + (size_t)e * R * C;
    const int c0 = blockIdx.x * 64, r0 = blockIdx.y * 64;
    const int t = threadIdx.x;
    const int rr = t >> 4, cc = (t & 15) * 4;
#pragma unroll
    for (int it = 0; it < 4; it++) {
        float4 v = *(const float4*)(in_e + (size_t)(r0 + rr + it * 16) * C + c0 + cc);
        Ls[rr + it * 16][cc + 0] = v.x;
        Ls[rr + it * 16][cc + 1] = v.y;
        Ls[rr + it * 16][cc + 2] = v.z;
        Ls[rr + it * 16][cc + 3] = v.w;
    }
    __syncthreads();
#pragma unroll
    for (int it = 0; it < 2; it++) {
        int idx = t + it * 256;
        int a = idx >> 3, b8 = (idx & 7) * 8;
        short8 v;
#pragma unroll
        for (int j = 0; j < 8; j++) v[j] = (short)f2bf(Ls[b8 + j][a]);
        *(short8*)(out_e + (size_t)(c0 + a) * R + r0 + b8) = v;
    }
}

// ---------------- pass A: Xg @ {w1,w2} + bias -> swiglu -> Hbuf (bf16) ----------------
// 128x128xBK32 tile, 4 waves x (64x64, 4x4 frags), dual acc.
// All staging via global_load_lds; LDS k-chunk-major: chunk o = kc*128+row at offset o*16B.
__global__ __launch_bounds__(256, 2) void ffn1_mfma_kernel(
    const unsigned short* __restrict__ Xbf,
    const unsigned short* __restrict__ W1T, const unsigned short* __restrict__ W2T,
    const float* __restrict__ b1, const float* __restrict__ b2,
    const int* __restrict__ counts, const int* __restrict__ lists,
    unsigned short* __restrict__ Hbuf)
{
    const int e = blockIdx.z;
    const int cnt = counts[e];
    const int m0 = blockIdx.y * 128;
    if (m0 >= cnt) return;
    const int n0 = blockIdx.x * 128;

    __shared__ __align__(16) unsigned short As[4096];   // 8 KB
    __shared__ __align__(16) unsigned short B1s[4096];
    __shared__ __align__(16) unsigned short B2s[4096];
    __shared__ int rowids[128];

    const int t = threadIdx.x;
    if (t < 128) {
        int idx = m0 + t;
        rowids[t] = (idx < cnt) ? lists[e * N_TOK + idx] : -1;
    }
    __syncthreads();

    // staging: thread t handles row (t&127), k-chunks kc_lo and kc_lo+2
    const int srow = t & 127;
    const int kc_lo = t >> 7;                     // 0/1
    const int rid_s = rowids[srow];
    const unsigned short* Ap  = Xbf + (size_t)(rid_s < 0 ? 0 : (rid_s >> 1)) * DIM;
    const unsigned short* W1p = W1T + (size_t)e * DIM * HID + (size_t)(n0 + srow) * DIM;
    const unsigned short* W2p = W2T + (size_t)e * DIM * HID + (size_t)(n0 + srow) * DIM;
    const int lb0 = (t & ~63) * 8;                // LDS short-index base, issue 0
    const int lb1 = (256 + (t & ~63)) * 8;        // issue 1

    f32x4 acc1[4][4], acc2[4][4];
    const f32x4 fz = {0.f, 0.f, 0.f, 0.f};
#pragma unroll
    for (int i = 0; i < 4; i++)
#pragma unroll
        for (int j = 0; j < 4; j++) { acc1[i][j] = fz; acc2[i][j] = fz; }

    const int lane = t & 63, wv = t >> 6;
    const int wm = (wv >> 1) * 64, wn = (wv & 1) * 64;
    const int fr = lane & 15, kq = lane >> 4;

    for (int k0 = 0; k0 < DIM; k0 += 32) {
        const int o0 = k0 + kc_lo * 8;            // shorts
        const int o1 = k0 + (kc_lo + 2) * 8;
        gl_lds16(Ap + o0,  As + lb0);
        gl_lds16(Ap + o1,  As + lb1);
        gl_lds16(W1p + o0, B1s + lb0);
        gl_lds16(W1p + o1, B1s + lb1);
        gl_lds16(W2p + o0, B2s + lb0);
        gl_lds16(W2p + o1, B2s + lb1);
        __syncthreads();

        short8 af[4];
#pragma unroll
        for (int mi = 0; mi < 4; mi++)
            af[mi] = *(const short8*)&As[(kq * 128 + wm + mi * 16 + fr) * 8];
#pragma unroll
        for (int ni = 0; ni < 4; ni++) {
            short8 bf1 = *(const short8*)&B1s[(kq * 128 + wn + ni * 16 + fr) * 8];
            short8 bf2 = *(const short8*)&B2s[(kq * 128 + wn + ni * 16 + fr) * 8];
#pragma unroll
            for (int mi = 0; mi < 4; mi++) {
                acc1[mi][ni] = __builtin_amdgcn_mfma_f32_16x16x32_bf16(af[mi], bf1, acc1[mi][ni], 0, 0, 0);
                acc2[mi][ni] = __builtin_amdgcn_mfma_f32_16x16x32_bf16(af[mi], bf2, acc2[mi][ni], 0, 0, 0);
            }
        }
        __syncthreads();
    }

    // epilogue: bias + swiglu, store bf16 H rows
#pragma unroll
    for (int ni = 0; ni < 4; ni++) {
        int col = n0 + wn + ni * 16 + fr;
        float bb1 = b1[e * HID + col];
        float bb2 = b2[e * HID + col];
#pragma unroll
        for (int mi = 0; mi < 4; mi++) {
#pragma unroll
            for (int j = 0; j < 4; j++) {
                int rl = wm + mi * 16 + kq * 4 + j;
                int rid = rowids[rl];
                if (rid < 0) continue;
                float v1 = acc1[mi][ni][j] + bb1;
                float v2 = acc2[mi][ni][j] + bb2;
                float h = v1 * (1.f / (1.f + __expf(-v2)));
                Hbuf[(size_t)rid * HID + col] = f2bf(h);
            }
        }
    }
}

// ---------------- pass B: Hg @ w3 + b3, scale, atomicAdd into out ----------------
__global__ __launch_bounds__(256, 2) void ffn2_mfma_kernel(
    const unsigned short* __restrict__ Hbuf,
    const unsigned short* __restrict__ W3T, const float* __restrict__ b3,
    const int* __restrict__ counts, const int* __restrict__ lists, const float* __restrict__ wts,
    float* __restrict__ out)
{
    const int e = blockIdx.z;
    const int cnt = counts[e];
    const int m0 = blockIdx.y * 128;
    if (m0 >= cnt) return;
    const int n0 = blockIdx.x * 128;

    __shared__ __align__(16) unsigned short As[4096];
    __shared__ __align__(16) unsigned short B3s[4096];
    __shared__ int rowids[128];
    __shared__ float rowwt[128];

    const int t = threadIdx.x;
    if (t < 128) {
        int idx = m0 + t;
        if (idx < cnt) { rowids[t] = lists[e * N_TOK + idx]; rowwt[t] = wts[e * N_TOK + idx]; }
        else           { rowids[t] = -1; rowwt[t] = 0.f; }
    }
    __syncthreads();

    const int srow = t & 127;
    const int kc_lo = t >> 7;
    const int rid_s = rowids[srow];
    const unsigned short* Ap  = Hbuf + (size_t)(rid_s < 0 ? 0 : rid_s) * HID;
    const unsigned short* W3p = W3T + (size_t)e * DIM * HID + (size_t)(n0 + srow) * HID;
    const int lb0 = (t & ~63) * 8;
    const int lb1 = (256 + (t & ~63)) * 8;

    f32x4 acc[4][4];
    const f32x4 fz = {0.f, 0.f, 0.f, 0.f};
#pragma unroll
    for (int i = 0; i < 4; i++)
#pragma unroll
        for (int j = 0; j < 4; j++) acc[i][j] = fz;

    const int lane = t & 63, wv = t >> 6;
    const int wm = (wv >> 1) * 64, wn = (wv & 1) * 64;
    const int fr = lane & 15, kq = lane >> 4;

    for (int k0 = 0; k0 < HID; k0 += 32) {
        const int o0 = k0 + kc_lo * 8;
        const int o1 = k0 + (kc_lo + 2) * 8;
        gl_lds16(Ap + o0,  As + lb0);
        gl_lds16(Ap + o1,  As + lb1);
        gl_lds16(W3p + o0, B3s + lb0);
        gl_lds16(W3p + o1, B3s + lb1);
        __syncthreads();

        short8 af[4];
#pragma unroll
        for (int mi = 0; mi < 4; mi++)
            af[mi] = *(const short8*)&As[(kq * 128 + wm + mi * 16 + fr) * 8];
#pragma unroll
        for (int ni = 0; ni < 4; ni++) {
            short8 bf3 = *(const short8*)&B3s[(kq * 128 + wn + ni * 16 + fr) * 8];
#pragma unroll
            for (int mi = 0; mi < 4; mi++)
                acc[mi][ni] = __builtin_amdgcn_mfma_f32_16x16x32_bf16(af[mi], bf3, acc[mi][ni], 0, 0, 0);
        }
        __syncthreads();
    }

#pragma unroll
    for (int ni = 0; ni < 4; ni++) {
        int col = n0 + wn + ni * 16 + fr;
        float bb3 = b3[e * DIM + col];
#pragma unroll
        for (int mi = 0; mi < 4; mi++) {
#pragma unroll
            for (int j = 0; j < 4; j++) {
                int rl = wm + mi * 16 + kq * 4 + j;
                int rid = rowids[rl];
                if (rid < 0) continue;
                float v = (acc[mi][ni][j] + bb3) * rowwt[rl];
                atomicAdd(&out[(size_t)(rid >> 1) * DIM + col], v);
            }
        }
    }
}

extern "C" void kernel_launch(void* const* d_in, const int* in_sizes, int n_in,
                              void* d_out, int out_size, void* d_ws, size_t ws_size,
                              hipStream_t stream) {
    (void)in_sizes; (void)n_in; (void)out_size; (void)ws_size;
    const float* x      = (const float*)d_in[0];
    const float* gate_w = (const float*)d_in[1];
    const float* gate_b = (const float*)d_in[2];
    const float* w1     = (const float*)d_in[3];
    const float* b1     = (const float*)d_in[4];
    const float* w2     = (const float*)d_in[5];
    const float* b2     = (const float*)d_in[6];
    const float* w3     = (const float*)d_in[7];
    const float* b3     = (const float*)d_in[8];
    float* out = (float*)d_out;

    char* ws = (char*)d_ws;
    float* usage  = (float*)ws;                                  // 32 B
    int*   counts = (int*)(ws + 32);                             // 32 B
    int*   lists  = (int*)(ws + 64);                             // 256 KB
    float* wts    = (float*)(ws + 64 + (size_t)NE * N_TOK * 4);  // 256 KB
    unsigned short* Hbuf = (unsigned short*)(ws + (1ull << 20));   // @1 MiB, 64 MiB
    unsigned short* W1T  = (unsigned short*)(ws + (65ull << 20));  // @65 MiB, 32 MiB
    unsigned short* W2T  = (unsigned short*)(ws + (97ull << 20));  // @97 MiB, 32 MiB
    unsigned short* W3T  = W1T;                                    // reused after ffn1
    // Xbf (16 MiB) lives in d_out during the first phase; memset after ffn1 re-zeroes it.
    unsigned short* Xbf  = (unsigned short*)d_out;

    hipMemsetAsync(ws, 0, 64, stream);

    gate_kernel<<<N_TOK / 4, 256, 0, stream>>>(x, gate_w, gate_b, usage, counts, lists, wts);
    xconv_kernel<<<N_TOK * DIM / (256 * 8), 256, 0, stream>>>(x, Xbf);

    dim3 gT1(HID / 64, DIM / 64, NE);
    transpose_bf16_kernel<<<gT1, 256, 0, stream>>>(w1, W1T, DIM, HID);
    transpose_bf16_kernel<<<gT1, 256, 0, stream>>>(w2, W2T, DIM, HID);

    dim3 gA(HID / 128, N_TOK / 128, NE);
    ffn1_mfma_kernel<<<gA, 256, 0, stream>>>(Xbf, W1T, W2T, b1, b2, counts, lists, Hbuf);

    // zero out (also wipes Xbf region), then loss into its slot
    hipMemsetAsync(d_out, 0, (size_t)N_TOK * DIM * sizeof(float), stream);
    loss_kernel<<<1, 64, 0, stream>>>(usage, out + (size_t)N_TOK * DIM);

    dim3 gT3(DIM / 64, HID / 64, NE);
    transpose_bf16_kernel<<<gT3, 256, 0, stream>>>(w3, W3T, HID, DIM);

    dim3 gB(DIM / 128, N_TOK / 128, NE);
    ffn2_mfma_kernel<<<gB, 256, 0, stream>>>(Hbuf, W3T, b3, counts, lists, wts, out);
}